// Round 1
// 483.854 us; speedup vs baseline: 1.0021x; 1.0021x over previous
//
#include <hip/hip_runtime.h>
#include <cstddef>

#define BATCH 16384
#define IN_F  4096
#define OUT_F 4096
#define ROWS_PER_BLOCK 16
#define NBLOCKS (BATCH / ROWS_PER_BLOCK)   // 1024 blocks, 4/CU, whole grid resident

// Keys cubic convolution, a = -0.75 (torch bicubic), align_corners=True.
__device__ __forceinline__ float cub_inner(float s) {
    return (1.25f * s - 2.25f) * s * s + 1.0f;
}
__device__ __forceinline__ float cub_outer(float s) {
    return ((-0.75f * s + 3.75f) * s - 6.0f) * s + 3.0f;
}

// Row i of the (4096, 4) cubic interpolation matrix (border-replicated).
__device__ __forceinline__ void cubic_row(int i, float& a0, float& a1, float& a2, float& a3) {
    const float inv = 3.0f / 4095.0f;
    const float xi = (float)i * inv;
    const float x0 = floorf(xi);
    const float t  = xi - x0;
    const int   c  = (int)x0;
    const float w0 = cub_outer(t + 1.0f);
    const float w1 = cub_inner(t);
    const float w2 = cub_inner(1.0f - t);
    const float w3 = cub_outer(2.0f - t);
    if (c == 0)      { a0 = w0 + w1; a1 = w2;   a2 = w3;   a3 = 0.0f; }
    else if (c == 1) { a0 = w0;      a1 = w1;   a2 = w2;   a3 = w3; }
    else if (c == 2) { a0 = 0.0f;    a1 = w0;   a2 = w1;   a3 = w2 + w3; }
    else             { a0 = 0.0f;    a1 = 0.0f; a2 = w0;   a3 = w1 + w2 + w3; }
}

// One-time table build (4096 threads, ~2 us):
//   Atab[i] = A_in row-i taps, Mtab[o] = (A_out @ CP) row-o, btab[o] = lerped bias.
__global__ __launch_bounds__(256) void k_init(const float* __restrict__ cp,
                                              const float* __restrict__ bcp,
                                              float4* __restrict__ Atab,
                                              float4* __restrict__ Mtab,
                                              float*  __restrict__ btab) {
    const int i = blockIdx.x * 256 + threadIdx.x;          // 0..4095
    float a0, a1, a2, a3;
    cubic_row(i, a0, a1, a2, a3);
    Atab[i] = make_float4(a0, a1, a2, a3);

    float4 m;
    m.x = a0 * cp[0] + a1 * cp[4] + a2 * cp[8]  + a3 * cp[12];
    m.y = a0 * cp[1] + a1 * cp[5] + a2 * cp[9]  + a3 * cp[13];
    m.z = a0 * cp[2] + a1 * cp[6] + a2 * cp[10] + a3 * cp[14];
    m.w = a0 * cp[3] + a1 * cp[7] + a2 * cp[11] + a3 * cp[15];
    Mtab[i] = m;

    const float xb = (float)i * (3.0f / 4095.0f);
    const float lo = floorf(xb);
    const float tb = xb - lo;
    const int   l  = (int)lo;
    const float b0 = bcp[0], b1 = bcp[1], b2 = bcp[2], b3 = bcp[3];
    const float blo = (l == 0) ? b0 : (l == 1) ? b1 : (l == 2) ? b2 : b3;
    const float bhi = (l >= 2) ? b3 : (l == 1) ? b2 : b1;
    btab[i] = (1.0f - tb) * blo + tb * bhi;
}

// Fused: per block, project 16 rows (phase A) then expand them (phase B).
// Tables live in registers across the 16 rows; only x-read + y-write touch HBM.
__global__ __launch_bounds__(256) void k_fused(const float* __restrict__ x,
                                               const float4* __restrict__ Atab,
                                               const float4* __restrict__ Mtab,
                                               const float4* __restrict__ btabv,
                                               float* __restrict__ y) {
    const int tid  = threadIdx.x;
    const int wid  = tid >> 6;
    const int lane = tid & 63;
    const int row0 = blockIdx.x * ROWS_PER_BLOCK;

    __shared__ float4 part[4][ROWS_PER_BLOCK];   // per-wave partial t-vectors (1 KB)

    // ---- phase A: t[r] = x[r] @ A_in, taps register-cached ----
    float4 Af[16];
#pragma unroll
    for (int k = 0; k < 4; ++k)
#pragma unroll
        for (int j = 0; j < 4; ++j)
            Af[k * 4 + j] = Atab[1024 * k + 4 * tid + j];

#pragma unroll 2
    for (int r = 0; r < ROWS_PER_BLOCK; ++r) {
        const float4* xr = (const float4*)(x + (size_t)(row0 + r) * IN_F);
        float s0 = 0.f, s1 = 0.f, s2 = 0.f, s3 = 0.f;
#pragma unroll
        for (int k = 0; k < 4; ++k) {
            const float4 xv = xr[k * 256 + tid];
            const float4 A0 = Af[k * 4 + 0], A1 = Af[k * 4 + 1];
            const float4 A2 = Af[k * 4 + 2], A3 = Af[k * 4 + 3];
            s0 += A0.x * xv.x + A1.x * xv.y + A2.x * xv.z + A3.x * xv.w;
            s1 += A0.y * xv.x + A1.y * xv.y + A2.y * xv.z + A3.y * xv.w;
            s2 += A0.z * xv.x + A1.z * xv.y + A2.z * xv.z + A3.z * xv.w;
            s3 += A0.w * xv.x + A1.w * xv.y + A2.w * xv.z + A3.w * xv.w;
        }
#pragma unroll
        for (int off = 32; off > 0; off >>= 1) {
            s0 += __shfl_down(s0, off);
            s1 += __shfl_down(s1, off);
            s2 += __shfl_down(s2, off);
            s3 += __shfl_down(s3, off);
        }
        if (lane == 0) part[wid][r] = make_float4(s0, s1, s2, s3);
    }
    __syncthreads();
    __builtin_amdgcn_sched_barrier(0);   // keep phase-B table loads out of phase A (VGPR)

    // ---- phase B: y[r] = M @ t[r] + bias, M rows register-cached ----
    float4 Mf[16];
    float4 bf[4];
#pragma unroll
    for (int k = 0; k < 4; ++k) {
#pragma unroll
        for (int j = 0; j < 4; ++j)
            Mf[k * 4 + j] = Mtab[1024 * k + 4 * tid + j];
        bf[k] = btabv[256 * k + tid];
    }

#pragma unroll 2
    for (int r = 0; r < ROWS_PER_BLOCK; ++r) {
        const float4 p0 = part[0][r], p1 = part[1][r], p2 = part[2][r], p3 = part[3][r];
        float4 u;
        u.x = (p0.x + p1.x) + (p2.x + p3.x);
        u.y = (p0.y + p1.y) + (p2.y + p3.y);
        u.z = (p0.z + p1.z) + (p2.z + p3.z);
        u.w = (p0.w + p1.w) + (p2.w + p3.w);
        float4* yr = (float4*)(y + (size_t)(row0 + r) * OUT_F);
#pragma unroll
        for (int k = 0; k < 4; ++k) {
            const float4 M0 = Mf[k * 4 + 0], M1 = Mf[k * 4 + 1];
            const float4 M2 = Mf[k * 4 + 2], M3 = Mf[k * 4 + 3];
            float4 o;
            o.x = bf[k].x + M0.x * u.x + M0.y * u.y + M0.z * u.z + M0.w * u.w;
            o.y = bf[k].y + M1.x * u.x + M1.y * u.y + M1.z * u.z + M1.w * u.w;
            o.z = bf[k].z + M2.x * u.x + M2.y * u.y + M2.z * u.z + M2.w * u.w;
            o.w = bf[k].w + M3.x * u.x + M3.y * u.y + M3.z * u.z + M3.w * u.w;
            yr[k * 256 + tid] = o;
        }
    }
}

extern "C" void kernel_launch(void* const* d_in, const int* in_sizes, int n_in,
                              void* d_out, int out_size, void* d_ws, size_t ws_size,
                              hipStream_t stream) {
    const float* x   = (const float*)d_in[0];   // (16384, 4096) f32
    const float* cp  = (const float*)d_in[1];   // (4, 4) f32
    const float* bcp = (const float*)d_in[2];   // (4,) f32
    float* y = (float*)d_out;                   // (16384, 4096) f32

    // workspace: Atab 64 KB | Mtab 64 KB | btab 16 KB  (ws >= 256 KB)
    float4* Atab = (float4*)d_ws;
    float4* Mtab = (float4*)((char*)d_ws + 64 * 1024);
    float*  btab = (float*)((char*)d_ws + 128 * 1024);

    k_init<<<dim3(IN_F / 256), dim3(256), 0, stream>>>(cp, bcp, Atab, Mtab, btab);
    k_fused<<<dim3(NBLOCKS), dim3(256), 0, stream>>>(x, Atab, Mtab, (const float4*)btab, y);
}

// Round 2
// 455.693 us; speedup vs baseline: 1.0640x; 1.0618x over previous
//
#include <hip/hip_runtime.h>
#include <cstddef>

#define BATCH 16384
#define IN_F  4096
#define OUT_F 4096
#define ROWS_PER_BLOCK 4
#define NBLOCKS (BATCH / ROWS_PER_BLOCK)   // 4096 blocks, 16/CU -> block turnover hides latency

// Keys cubic convolution, a = -0.75 (torch bicubic), align_corners=True.
__device__ __forceinline__ float cub_inner(float s) {
    return (1.25f * s - 2.25f) * s * s + 1.0f;
}
__device__ __forceinline__ float cub_outer(float s) {
    return ((-0.75f * s + 3.75f) * s - 6.0f) * s + 3.0f;
}

// Row i of the (4096, 4) cubic interpolation matrix (border-replicated).
__device__ __forceinline__ void cubic_row(int i, float& a0, float& a1, float& a2, float& a3) {
    const float inv = 3.0f / 4095.0f;
    const float xi = (float)i * inv;
    const float x0 = floorf(xi);
    const float t  = xi - x0;
    const int   c  = (int)x0;
    const float w0 = cub_outer(t + 1.0f);
    const float w1 = cub_inner(t);
    const float w2 = cub_inner(1.0f - t);
    const float w3 = cub_outer(2.0f - t);
    if (c == 0)      { a0 = w0 + w1; a1 = w2;   a2 = w3;   a3 = 0.0f; }
    else if (c == 1) { a0 = w0;      a1 = w1;   a2 = w2;   a3 = w3; }
    else if (c == 2) { a0 = 0.0f;    a1 = w0;   a2 = w1;   a3 = w2 + w3; }
    else             { a0 = 0.0f;    a1 = 0.0f; a2 = w0;   a3 = w1 + w2 + w3; }
}

// One-time table build (4096 threads, ~2 us):
//   Atab[i] = A_in row-i taps, Mtab[o] = (A_out @ CP) row-o, btab[o] = lerped bias.
__global__ __launch_bounds__(256) void k_init(const float* __restrict__ cp,
                                              const float* __restrict__ bcp,
                                              float4* __restrict__ Atab,
                                              float4* __restrict__ Mtab,
                                              float*  __restrict__ btab) {
    const int i = blockIdx.x * 256 + threadIdx.x;          // 0..4095
    float a0, a1, a2, a3;
    cubic_row(i, a0, a1, a2, a3);
    Atab[i] = make_float4(a0, a1, a2, a3);

    float4 m;
    m.x = a0 * cp[0] + a1 * cp[4] + a2 * cp[8]  + a3 * cp[12];
    m.y = a0 * cp[1] + a1 * cp[5] + a2 * cp[9]  + a3 * cp[13];
    m.z = a0 * cp[2] + a1 * cp[6] + a2 * cp[10] + a3 * cp[14];
    m.w = a0 * cp[3] + a1 * cp[7] + a2 * cp[11] + a3 * cp[15];
    Mtab[i] = m;

    const float xb = (float)i * (3.0f / 4095.0f);
    const float lo = floorf(xb);
    const float tb = xb - lo;
    const int   l  = (int)lo;
    const float b0 = bcp[0], b1 = bcp[1], b2 = bcp[2], b3 = bcp[3];
    const float blo = (l == 0) ? b0 : (l == 1) ? b1 : (l == 2) ? b2 : b3;
    const float bhi = (l >= 2) ? b3 : (l == 1) ? b2 : b1;
    btab[i] = (1.0f - tb) * blo + tb * bhi;
}

// Fused: per block, project 4 rows (phase A, deferred batched reduce) then expand.
__global__ __launch_bounds__(256) void k_fused(const float* __restrict__ x,
                                               const float4* __restrict__ Atab,
                                               const float4* __restrict__ Mtab,
                                               const float4* __restrict__ btabv,
                                               float* __restrict__ y) {
    const int tid  = threadIdx.x;
    const int wid  = tid >> 6;
    const int lane = tid & 63;
    const int row0 = blockIdx.x * ROWS_PER_BLOCK;

    __shared__ float4 part[4][ROWS_PER_BLOCK];   // per-wave partial t-vectors (256 B)

    // ---- phase A: acc[r] = partial of x[row0+r] @ A_in, taps register-cached ----
    float4 Af[16];
#pragma unroll
    for (int k = 0; k < 4; ++k)
#pragma unroll
        for (int j = 0; j < 4; ++j)
            Af[k * 4 + j] = Atab[1024 * k + 4 * tid + j];

    float4 acc[ROWS_PER_BLOCK];
#pragma unroll
    for (int r = 0; r < ROWS_PER_BLOCK; ++r) {
        const float4* xr = (const float4*)(x + (size_t)(row0 + r) * IN_F);
        float s0 = 0.f, s1 = 0.f, s2 = 0.f, s3 = 0.f;
#pragma unroll
        for (int k = 0; k < 4; ++k) {
            const float4 xv = xr[k * 256 + tid];
            const float4 A0 = Af[k * 4 + 0], A1 = Af[k * 4 + 1];
            const float4 A2 = Af[k * 4 + 2], A3 = Af[k * 4 + 3];
            s0 += A0.x * xv.x + A1.x * xv.y + A2.x * xv.z + A3.x * xv.w;
            s1 += A0.y * xv.x + A1.y * xv.y + A2.y * xv.z + A3.y * xv.w;
            s2 += A0.z * xv.x + A1.z * xv.y + A2.z * xv.z + A3.z * xv.w;
            s3 += A0.w * xv.x + A1.w * xv.y + A2.w * xv.z + A3.w * xv.w;
        }
        acc[r] = make_float4(s0, s1, s2, s3);
    }

    // one batched reduction phase: 16 independent 6-level shuffle chains
#pragma unroll
    for (int off = 32; off > 0; off >>= 1) {
#pragma unroll
        for (int r = 0; r < ROWS_PER_BLOCK; ++r) {
            acc[r].x += __shfl_down(acc[r].x, off);
            acc[r].y += __shfl_down(acc[r].y, off);
            acc[r].z += __shfl_down(acc[r].z, off);
            acc[r].w += __shfl_down(acc[r].w, off);
        }
    }
    if (lane == 0) {
#pragma unroll
        for (int r = 0; r < ROWS_PER_BLOCK; ++r) part[wid][r] = acc[r];
    }
    __syncthreads();
    __builtin_amdgcn_sched_barrier(0);   // keep phase-B table loads out of phase A (VGPR)

    // ---- phase B: y[r] = M @ t[r] + bias, M rows register-cached ----
    float4 Mf[16];
    float4 bf[4];
#pragma unroll
    for (int k = 0; k < 4; ++k) {
#pragma unroll
        for (int j = 0; j < 4; ++j)
            Mf[k * 4 + j] = Mtab[1024 * k + 4 * tid + j];
        bf[k] = btabv[256 * k + tid];
    }

#pragma unroll
    for (int r = 0; r < ROWS_PER_BLOCK; ++r) {
        const float4 p0 = part[0][r], p1 = part[1][r], p2 = part[2][r], p3 = part[3][r];
        float4 u;
        u.x = (p0.x + p1.x) + (p2.x + p3.x);
        u.y = (p0.y + p1.y) + (p2.y + p3.y);
        u.z = (p0.z + p1.z) + (p2.z + p3.z);
        u.w = (p0.w + p1.w) + (p2.w + p3.w);
        float4* yr = (float4*)(y + (size_t)(row0 + r) * OUT_F);
#pragma unroll
        for (int k = 0; k < 4; ++k) {
            const float4 M0 = Mf[k * 4 + 0], M1 = Mf[k * 4 + 1];
            const float4 M2 = Mf[k * 4 + 2], M3 = Mf[k * 4 + 3];
            float4 o;
            o.x = bf[k].x + M0.x * u.x + M0.y * u.y + M0.z * u.z + M0.w * u.w;
            o.y = bf[k].y + M1.x * u.x + M1.y * u.y + M1.z * u.z + M1.w * u.w;
            o.z = bf[k].z + M2.x * u.x + M2.y * u.y + M2.z * u.z + M2.w * u.w;
            o.w = bf[k].w + M3.x * u.x + M3.y * u.y + M3.z * u.z + M3.w * u.w;
            yr[k * 256 + tid] = o;
        }
    }
}

extern "C" void kernel_launch(void* const* d_in, const int* in_sizes, int n_in,
                              void* d_out, int out_size, void* d_ws, size_t ws_size,
                              hipStream_t stream) {
    const float* x   = (const float*)d_in[0];   // (16384, 4096) f32
    const float* cp  = (const float*)d_in[1];   // (4, 4) f32
    const float* bcp = (const float*)d_in[2];   // (4,) f32
    float* y = (float*)d_out;                   // (16384, 4096) f32

    // workspace: Atab 64 KB | Mtab 64 KB | btab 16 KB  (ws >= 256 KB)
    float4* Atab = (float4*)d_ws;
    float4* Mtab = (float4*)((char*)d_ws + 64 * 1024);
    float*  btab = (float*)((char*)d_ws + 128 * 1024);

    k_init<<<dim3(IN_F / 256), dim3(256), 0, stream>>>(cp, bcp, Atab, Mtab, btab);
    k_fused<<<dim3(NBLOCKS), dim3(256), 0, stream>>>(x, Atab, Mtab, (const float4*)btab, y);
}

// Round 3
// 447.632 us; speedup vs baseline: 1.0832x; 1.0180x over previous
//
#include <hip/hip_runtime.h>
#include <cstddef>

#define BATCH 16384
#define IN_F  4096
#define OUT_F 4096
#define RPG    4                        // rows per pipeline group
#define GROUPS 8
#define ROWS_PER_BLOCK (RPG * GROUPS)   // 32
#define NBLOCKS (BATCH / ROWS_PER_BLOCK) // 512 blocks x 512 threads

// Keys cubic convolution, a = -0.75 (torch bicubic), align_corners=True.
__device__ __forceinline__ float cub_inner(float s) {
    return (1.25f * s - 2.25f) * s * s + 1.0f;
}
__device__ __forceinline__ float cub_outer(float s) {
    return ((-0.75f * s + 3.75f) * s - 6.0f) * s + 3.0f;
}

// Row i of the (4096, 4) cubic interpolation matrix (border-replicated).
__device__ __forceinline__ void cubic_row(int i, float& a0, float& a1, float& a2, float& a3) {
    const float inv = 3.0f / 4095.0f;
    const float xi = (float)i * inv;
    const float x0 = floorf(xi);
    const float t  = xi - x0;
    const int   c  = (int)x0;
    const float w0 = cub_outer(t + 1.0f);
    const float w1 = cub_inner(t);
    const float w2 = cub_inner(1.0f - t);
    const float w3 = cub_outer(2.0f - t);
    if (c == 0)      { a0 = w0 + w1; a1 = w2;   a2 = w3;   a3 = 0.0f; }
    else if (c == 1) { a0 = w0;      a1 = w1;   a2 = w2;   a3 = w3; }
    else if (c == 2) { a0 = 0.0f;    a1 = w0;   a2 = w1;   a3 = w2 + w3; }
    else             { a0 = 0.0f;    a1 = 0.0f; a2 = w0;   a3 = w1 + w2 + w3; }
}

// One-time table build (4096 threads, ~2 us):
//   Atab[i] = A_in row-i taps, Mtab[o] = (A_out @ CP) row-o, btab[o] = lerped bias.
__global__ __launch_bounds__(256) void k_init(const float* __restrict__ cp,
                                              const float* __restrict__ bcp,
                                              float4* __restrict__ Atab,
                                              float4* __restrict__ Mtab,
                                              float*  __restrict__ btab) {
    const int i = blockIdx.x * 256 + threadIdx.x;          // 0..4095
    float a0, a1, a2, a3;
    cubic_row(i, a0, a1, a2, a3);
    Atab[i] = make_float4(a0, a1, a2, a3);

    float4 m;
    m.x = a0 * cp[0] + a1 * cp[4] + a2 * cp[8]  + a3 * cp[12];
    m.y = a0 * cp[1] + a1 * cp[5] + a2 * cp[9]  + a3 * cp[13];
    m.z = a0 * cp[2] + a1 * cp[6] + a2 * cp[10] + a3 * cp[14];
    m.w = a0 * cp[3] + a1 * cp[7] + a2 * cp[11] + a3 * cp[15];
    Mtab[i] = m;

    const float xb = (float)i * (3.0f / 4095.0f);
    const float lo = floorf(xb);
    const float tb = xb - lo;
    const int   l  = (int)lo;
    const float b0 = bcp[0], b1 = bcp[1], b2 = bcp[2], b3 = bcp[3];
    const float blo = (l == 0) ? b0 : (l == 1) ? b1 : (l == 2) ? b2 : b3;
    const float bhi = (l >= 2) ? b3 : (l == 1) ? b2 : b1;
    btab[i] = (1.0f - tb) * blo + tb * bhi;
}

// Producer/consumer fused kernel.
//   waves 0-3 (256 thr): read x, project onto A_in taps, wave-reduce, post
//                        per-wave partial t-vectors to a 2-deep LDS buffer.
//   waves 4-7 (256 thr): sum partials, expand through M = A_out@CP, store y.
// Between consecutive barriers, group g+1's HBM reads run concurrently with
// group g's HBM writes -> both memory directions stay busy (round-2's
// phase-bursty duty cycle was the limiter: 2.7 TB/s of a 6.3 TB/s ceiling).
__global__ __launch_bounds__(512) void k_fused(const float* __restrict__ x,
                                               const float4* __restrict__ Atab,
                                               const float4* __restrict__ Mtab,
                                               const float4* __restrict__ btabv,
                                               float* __restrict__ y) {
    const int tid  = threadIdx.x;
    const int wid  = tid >> 6;
    const int lane = tid & 63;
    const int row0 = blockIdx.x * ROWS_PER_BLOCK;

    __shared__ float4 part[2][RPG][4];   // [buf][row-in-group][producer wave]

    if (wid < 4) {
        // ---------------- producer ----------------
        const int p = tid;               // 0..255
        float4 Af[16];
#pragma unroll
        for (int k = 0; k < 4; ++k)
#pragma unroll
            for (int j = 0; j < 4; ++j)
                Af[k * 4 + j] = Atab[1024 * k + 4 * p + j];

        auto produce = [&](int g) {
            const float* xg = x + (size_t)(row0 + g * RPG) * IN_F;
            float4 acc[RPG];
#pragma unroll
            for (int r = 0; r < RPG; ++r) {
                const float4* xr = (const float4*)(xg + (size_t)r * IN_F);
                float s0 = 0.f, s1 = 0.f, s2 = 0.f, s3 = 0.f;
#pragma unroll
                for (int k = 0; k < 4; ++k) {
                    const float4 xv = xr[k * 256 + p];
                    const float4 A0 = Af[k * 4 + 0], A1 = Af[k * 4 + 1];
                    const float4 A2 = Af[k * 4 + 2], A3 = Af[k * 4 + 3];
                    s0 += A0.x * xv.x + A1.x * xv.y + A2.x * xv.z + A3.x * xv.w;
                    s1 += A0.y * xv.x + A1.y * xv.y + A2.y * xv.z + A3.y * xv.w;
                    s2 += A0.z * xv.x + A1.z * xv.y + A2.z * xv.z + A3.z * xv.w;
                    s3 += A0.w * xv.x + A1.w * xv.y + A2.w * xv.z + A3.w * xv.w;
                }
                acc[r] = make_float4(s0, s1, s2, s3);
            }
            // batched reduce: RPG*4 independent shuffle chains
#pragma unroll
            for (int off = 32; off > 0; off >>= 1)
#pragma unroll
                for (int r = 0; r < RPG; ++r) {
                    acc[r].x += __shfl_down(acc[r].x, off);
                    acc[r].y += __shfl_down(acc[r].y, off);
                    acc[r].z += __shfl_down(acc[r].z, off);
                    acc[r].w += __shfl_down(acc[r].w, off);
                }
            if (lane == 0) {
#pragma unroll
                for (int r = 0; r < RPG; ++r) part[g & 1][r][wid] = acc[r];
            }
        };

        produce(0);
        __syncthreads();
        for (int g = 0; g < GROUPS; ++g) {
            if (g + 1 < GROUPS) produce(g + 1);   // reads overlap consumer's writes
            __syncthreads();
        }
    } else {
        // ---------------- consumer ----------------
        const int c = tid - 256;         // 0..255
        float4 Mf[16];
        float4 bf[4];
#pragma unroll
        for (int k = 0; k < 4; ++k) {
#pragma unroll
            for (int j = 0; j < 4; ++j)
                Mf[k * 4 + j] = Mtab[1024 * k + 4 * c + j];
            bf[k] = btabv[256 * k + c];
        }

        __syncthreads();
        for (int g = 0; g < GROUPS; ++g) {
#pragma unroll
            for (int r = 0; r < RPG; ++r) {
                const float4 p0 = part[g & 1][r][0], p1 = part[g & 1][r][1];
                const float4 p2 = part[g & 1][r][2], p3 = part[g & 1][r][3];
                float4 u;
                u.x = (p0.x + p1.x) + (p2.x + p3.x);
                u.y = (p0.y + p1.y) + (p2.y + p3.y);
                u.z = (p0.z + p1.z) + (p2.z + p3.z);
                u.w = (p0.w + p1.w) + (p2.w + p3.w);
                float4* yr = (float4*)(y + (size_t)(row0 + g * RPG + r) * OUT_F);
#pragma unroll
                for (int k = 0; k < 4; ++k) {
                    const float4 M0 = Mf[k * 4 + 0], M1 = Mf[k * 4 + 1];
                    const float4 M2 = Mf[k * 4 + 2], M3 = Mf[k * 4 + 3];
                    float4 o;
                    o.x = bf[k].x + M0.x * u.x + M0.y * u.y + M0.z * u.z + M0.w * u.w;
                    o.y = bf[k].y + M1.x * u.x + M1.y * u.y + M1.z * u.z + M1.w * u.w;
                    o.z = bf[k].z + M2.x * u.x + M2.y * u.y + M2.z * u.z + M2.w * u.w;
                    o.w = bf[k].w + M3.x * u.x + M3.y * u.y + M3.z * u.z + M3.w * u.w;
                    yr[k * 256 + c] = o;
                }
            }
            __syncthreads();
        }
    }
}

extern "C" void kernel_launch(void* const* d_in, const int* in_sizes, int n_in,
                              void* d_out, int out_size, void* d_ws, size_t ws_size,
                              hipStream_t stream) {
    const float* x   = (const float*)d_in[0];   // (16384, 4096) f32
    const float* cp  = (const float*)d_in[1];   // (4, 4) f32
    const float* bcp = (const float*)d_in[2];   // (4,) f32
    float* y = (float*)d_out;                   // (16384, 4096) f32

    // workspace: Atab 64 KB | Mtab 64 KB | btab 16 KB  (ws >= 256 KB)
    float4* Atab = (float4*)d_ws;
    float4* Mtab = (float4*)((char*)d_ws + 64 * 1024);
    float*  btab = (float*)((char*)d_ws + 128 * 1024);

    k_init<<<dim3(IN_F / 256), dim3(256), 0, stream>>>(cp, bcp, Atab, Mtab, btab);
    k_fused<<<dim3(NBLOCKS), dim3(512), 0, stream>>>(x, Atab, Mtab, (const float4*)btab, y);
}